// Round 1
// baseline (220.621 us; speedup 1.0000x reference)
//
#include <hip/hip_runtime.h>
#include <hip/hip_bf16.h>

namespace {

constexpr int kN = 64, kC = 128, kT = 128, kV = 25, kH = 8, kc = 16;
constexpr int kMPad = 416;                  // 400 output cols padded to 26*16
constexpr int kBlkShorts = 4 * kMPad * 8;   // 13312 bf16 per (h,c) weight block

typedef __attribute__((ext_vector_type(8))) short bf16x8;
typedef __attribute__((ext_vector_type(4))) float f32x4;

__device__ inline unsigned short f2bf(float f) {
    unsigned int u = __builtin_bit_cast(unsigned int, f);
    u += 0x7fffu + ((u >> 16) & 1u);   // round-to-nearest-even
    return (unsigned short)(u >> 16);
}

// ---------------- P1: w1_i[h][v][w] = fc1/||.|| + pe/||.||  (norm over v) ----
__global__ void precompute_w1(const float* __restrict__ fc1,
                              const float* __restrict__ rpe,
                              const int* __restrict__ hops,
                              float* __restrict__ W1) {
    int ih = blockIdx.x;        // i*8+h, 0..23
    int w = threadIdx.x;
    if (w >= kV) return;
    const float* f = fc1 + ih * kV * kV;
    const float* r = rpe + ih * kV;
    float s1 = 0.f, s2 = 0.f;
    for (int v = 0; v < kV; ++v) {
        float a = f[v * kV + w];
        float p = r[hops[v * kV + w]];
        s1 += a * a; s2 += p * p;
    }
    float n1 = sqrtf(s1) + 1e-4f, n2 = sqrtf(s2) + 1e-4f;
    float* o = W1 + ih * kV * kV;
    for (int v = 0; v < kV; ++v) {
        float a = f[v * kV + w];
        float p = r[hops[v * kV + w]];
        o[v * kV + w] = a / n1 + p / n2;
    }
}

// ---------------- P2: combined weight, staging-order layout ------------------
// Wt2[h][c][kg][m][j] (bf16), m padded to 416, v = kg*8+j (>=25 -> 0)
// element = sum_i wg_i[h, d=m/25, c] * w1_i[h, v, w=m%25]
__global__ void precompute_W(const float* __restrict__ W1,
                             const float* __restrict__ fc2_w,
                             unsigned short* __restrict__ Wt2) {
    int cb = blockIdx.x;        // 0..15
    int h  = blockIdx.y;        // 0..7
    unsigned short* outp = Wt2 + (size_t)(h * 16 + cb) * kBlkShorts;
    for (int e = threadIdx.x; e < kBlkShorts; e += 256) {
        int kg  = e / (kMPad * 8);
        int rem = e - kg * (kMPad * 8);
        int m = rem >> 3;
        int j = rem & 7;
        int v = kg * 8 + j;
        float val = 0.f;
        if (v < kV && m < 400) {
            int d = m / kV, w = m - d * kV;
            #pragma unroll
            for (int i = 0; i < 3; ++i) {
                float wg = fc2_w[(i * kC + h * kc + d) * kc + cb];
                float w1 = W1[((i * kH + h) * kV + v) * kV + w];
                val += wg * w1;
            }
        }
        outp[e] = f2bf(val);
    }
}

// ---------------- A: y = x * W  (per head, MFMA bf16) ------------------------
// rows r=(n,t): 8192; cols m=(d,w): 400(->416); K = 16 c-steps of 32 (v pad)
__global__ __launch_bounds__(256) void gemm_y(const float* __restrict__ x,
                                              const unsigned short* __restrict__ Wt2,
                                              float* __restrict__ y) {
    __shared__ __align__(16) unsigned short Alds[4][64][8];     // [kg][row][j]
    __shared__ __align__(16) unsigned short Blds[4][kMPad][8];  // [kg][m][j]

    const int rb = blockIdx.x;      // 0..127
    const int h  = blockIdx.y;      // 0..7
    const int n  = rb >> 1;
    const int t0 = (rb & 1) * 64;
    const int tid  = threadIdx.x;
    const int lane = tid & 63;
    const int wv = tid >> 6;        // wave 0..3
    const int wr = wv >> 1;         // row half (32 rows)
    const int wc = wv & 1;          // col half (13 col-tiles each, padded)
    const int ll = lane & 15, lh = lane >> 4;
    const int ct0 = wc * 13;

    f32x4 acc[2][13];
    #pragma unroll
    for (int a = 0; a < 2; ++a)
        #pragma unroll
        for (int b = 0; b < 13; ++b) acc[a][b] = (f32x4)(0.f);

    const int arow = tid & 63;      // A-staging assignment
    const int akg  = tid >> 6;
    const unsigned short* wtb = Wt2 + (size_t)(h * 16) * kBlkShorts;

    for (int c = 0; c < 16; ++c) {
        // stage A: x[n][h*16+c][t0+row][v] -> bf16, v padded to 32
        const float* xr = x + ((size_t)(n * kC + h * kc + c) * kT + (t0 + arow)) * kV;
        bf16x8 ap;
        #pragma unroll
        for (int j = 0; j < 8; ++j) {
            int v = akg * 8 + j;
            float f = (v < kV) ? xr[v] : 0.f;
            ap[j] = (short)f2bf(f);
        }
        *((bf16x8*)&Alds[akg][arow][0]) = ap;

        // stage B: contiguous 16B chunks, coalesced
        const bf16x8* wsrc = (const bf16x8*)(wtb + (size_t)c * kBlkShorts);
        bf16x8* bdst = (bf16x8*)&Blds[0][0][0];
        for (int e = tid; e < kBlkShorts / 8; e += 256) bdst[e] = wsrc[e];

        __syncthreads();

        bf16x8 af0 = *((const bf16x8*)&Alds[lh][wr * 32 + ll][0]);
        bf16x8 af1 = *((const bf16x8*)&Alds[lh][wr * 32 + 16 + ll][0]);
        #pragma unroll
        for (int ci = 0; ci < 13; ++ci) {
            int mrow = (ct0 + ci) * 16 + ll;
            bf16x8 bf = *((const bf16x8*)&Blds[lh][mrow][0]);
            acc[0][ci] = __builtin_amdgcn_mfma_f32_16x16x32_bf16(af0, bf, acc[0][ci], 0, 0, 0);
            acc[1][ci] = __builtin_amdgcn_mfma_f32_16x16x32_bf16(af1, bf, acc[1][ci], 0, 0, 0);
        }
        __syncthreads();
    }

    // epilogue: D lane map col=lane&15, row=(lane>>4)*4+reg
    #pragma unroll
    for (int rt = 0; rt < 2; ++rt) {
        int t = t0 + wr * 32 + rt * 16 + lh * 4;
        #pragma unroll
        for (int ci = 0; ci < 13; ++ci) {
            int m = (ct0 + ci) * 16 + ll;
            if (m < 400) {
                int d = m / kV, w = m - d * kV;
                float* yp = y + ((size_t)(n * kC + h * kc + d) * kT) * kV + w;
                #pragma unroll
                for (int r = 0; r < 4; ++r)
                    yp[(size_t)(t + r) * kV] = acc[rt][ci][r];
            }
        }
    }
}

// ---------------- B1/B2: deterministic per-channel BN stats ------------------
__global__ void bn_partial(const float* __restrict__ y, float2* __restrict__ partials) {
    int g  = blockIdx.x;    // 0..7 (n-split)
    int ch = blockIdx.y;    // 0..127
    int tid = threadIdx.x;
    float s = 0.f, ss = 0.f;
    for (int n = g * 8; n < g * 8 + 8; ++n) {
        const float* p = y + (size_t)(n * kC + ch) * kT * kV;
        for (int e = tid; e < kT * kV; e += 256) {
            float v = p[e];
            s += v; ss += v * v;
        }
    }
    __shared__ float rs[256], rss[256];
    rs[tid] = s; rss[tid] = ss;
    __syncthreads();
    for (int o = 128; o > 0; o >>= 1) {
        if (tid < o) { rs[tid] += rs[tid + o]; rss[tid] += rss[tid + o]; }
        __syncthreads();
    }
    if (tid == 0) partials[ch * 8 + g] = make_float2(rs[0], rss[0]);
}

__global__ void bn_finalize(const float2* __restrict__ partials,
                            const float* __restrict__ gamma,
                            const float* __restrict__ beta,
                            float2* __restrict__ scsh) {
    int ch = threadIdx.x;
    if (ch >= kC) return;
    float s = 0.f, ss = 0.f;
    for (int g = 0; g < 8; ++g) {
        float2 p = partials[ch * 8 + g];
        s += p.x; ss += p.y;
    }
    const float inv = 1.f / (float)(kN * kT * kV);
    float mean = s * inv;
    float var  = ss * inv - mean * mean;
    float sc = gamma[ch] * rsqrtf(var + 1e-5f);
    scsh[ch] = make_float2(sc, beta[ch] - mean * sc);
}

// ---------------- C: out = relu(y*scale + shift + x), in place ---------------
__global__ void bn_apply(float* __restrict__ y, const float* __restrict__ x,
                         const float2* __restrict__ scsh) {
    const size_t total4 = (size_t)kN * kC * kT * kV / 4;   // 6,553,600
    for (size_t i = (size_t)blockIdx.x * blockDim.x + threadIdx.x; i < total4;
         i += (size_t)gridDim.x * blockDim.x) {
        int ch = (int)((i / 800) % kC);          // T*V/4 = 800 float4 per (n,ch)
        float2 sc = scsh[ch];
        f32x4 yv = ((const f32x4*)y)[i];
        f32x4 xv = ((const f32x4*)x)[i];
        f32x4 o;
        #pragma unroll
        for (int q = 0; q < 4; ++q)
            o[q] = fmaxf(yv[q] * sc.x + sc.y + xv[q], 0.f);
        ((f32x4*)y)[i] = o;
    }
}

} // namespace

extern "C" void kernel_launch(void* const* d_in, const int* in_sizes, int n_in,
                              void* d_out, int out_size, void* d_ws, size_t ws_size,
                              hipStream_t stream) {
    const float* x     = (const float*)d_in[0];
    const float* fc1   = (const float*)d_in[1];
    const float* rpe   = (const float*)d_in[2];
    const int*   hops  = (const int*)d_in[3];
    const float* fc2w  = (const float*)d_in[4];
    // d_in[5] = fc2_b: per-channel constant over BN axes -> cancelled by BN. Unused.
    const float* gamma = (const float*)d_in[6];
    const float* beta  = (const float*)d_in[7];
    float* y = (float*)d_out;

    char* ws = (char*)d_ws;
    float*          W1       = (float*)ws;                            // 60,000 B
    unsigned short* Wt2      = (unsigned short*)(ws + 65536);         // 3,407,872 B
    float2*         partials = (float2*)(ws + 65536 + 3407872);       // 8,192 B
    float2*         scsh     = (float2*)(ws + 65536 + 3407872 + 8192);// 1,024 B

    precompute_w1<<<24, 32, 0, stream>>>(fc1, rpe, hops, W1);
    precompute_W<<<dim3(16, 8), 256, 0, stream>>>(W1, fc2w, Wt2);
    gemm_y<<<dim3(128, 8), 256, 0, stream>>>(x, Wt2, y);
    bn_partial<<<dim3(8, 128), 256, 0, stream>>>(y, partials);
    bn_finalize<<<1, 128, 0, stream>>>(partials, gamma, beta, scsh);
    bn_apply<<<2048, 256, 0, stream>>>(y, x, scsh);
}